// Round 4
// baseline (1646.690 us; speedup 1.0000x reference)
//
#include <hip/hip_runtime.h>
#include <cstdint>
#include <type_traits>

namespace {

constexpr int ROWS = 256;            // B*C
constexpr int ROW_N = 65536;         // H*W
constexpr int ST = 1024;             // threads per sort block (16 waves)
constexpr int WAVES = 16;
constexpr int SEG = ROW_N / WAVES;   // 4096 elems per wave segment
constexpr int ITERS = SEG / 64;      // 64 groups per wave per pass
constexpr size_t NTOT = (size_t)ROWS * ROW_N;

constexpr float COS_02PI = 0.80901699437494745f;  // cos(0.2*pi)
constexpr float COS_04PI = 0.30901699437494745f;  // cos(0.4*pi)

struct SortSmem {
    __align__(16) uint32_t whist[WAVES * 256]; // 16 KB (wave, digit) table
    uint32_t wtot[4];
};

__device__ __forceinline__ uint32_t fkey(float x) {
    return __float_as_uint(fabsf(x));  // monotone for non-negative floats
}

// Stable LSD radix sort of one row, 3 x 8-bit passes on top-24 bits of |x|.
// Per pass: phase A streams the segment rebuilding the per-(wave,digit)
// histogram in REGISTERS via ballot bit-planes; one block scan; phase B
// scatters with register counters — no LDS atomics anywhere, 3 barriers/pass.
// src: u64 = k24<<16 | idx | sign(c)<<48 | sign(s)<<49 ; tgt: u32 full key.
// Final pass writes compact u32 into rowF (row's own retired slice).
template <bool IS_SRC>
__device__ void sort_row(SortSmem& sm, const float* __restrict__ raw,
                         const float* __restrict__ raw2,
                         void* bufA, void* bufB, uint32_t* __restrict__ rowF,
                         int row)
{
    using ELEM = std::conditional_t<IS_SRC, uint64_t, uint32_t>;
    const int tid = threadIdx.x;
    const int lane = tid & 63;
    const int wave = tid >> 6;
    const uint64_t lane_lt = (1ull << lane) - 1ull;

    const float* rawRow = raw + (size_t)row * ROW_N;
    const float* raw2Row = IS_SRC ? (raw2 + (size_t)row * ROW_N) : nullptr;
    ELEM* A = (ELEM*)bufA + (size_t)row * ROW_N;
    ELEM* B = (ELEM*)bufB + (size_t)row * ROW_N;

#pragma unroll
    for (int p = 0; p < 3; ++p) {
        // ---------- Phase A: per-wave digit histogram in registers ----------
        uint32_t C0 = 0u, C1 = 0u, C2 = 0u, C3 = 0u;
        {
            auto dig = [&](int it) -> uint32_t {
                const int gi = wave * SEG + it * 64 + lane;
                if (p == 0) return (fkey(rawRow[gi]) >> 7) & 255u;
                if constexpr (IS_SRC) {
                    const uint32_t* w = (const uint32_t*)((p == 1) ? A : B);
                    if (p == 1) return w[2 * gi] >> 24;       // e bits 24-31
                    else        return w[2 * gi + 1] & 255u;  // e bits 32-39
                } else {
                    const uint32_t* w = (const uint32_t*)((p == 1) ? A : B);
                    return ((w[gi] >> 7) >> (8 * p)) & 255u;
                }
            };
            uint32_t d = dig(0);
            for (int it = 0; it < ITERS; ++it) {
                uint32_t dn = 0u;
                if (it + 1 < ITERS) dn = dig(it + 1);   // prefetch
                const uint64_t b0 = __ballot(d & 1u),  b1 = __ballot(d & 2u);
                const uint64_t b2 = __ballot(d & 4u),  b3 = __ballot(d & 8u);
                const uint64_t b4 = __ballot(d & 16u), b5 = __ballot(d & 32u);
                const uint64_t b6 = __ballot(d & 64u), b7 = __ballot(d & 128u);
                uint64_t M = (lane & 1 ? b0 : ~b0);
                M &= (lane & 2 ? b1 : ~b1);
                M &= (lane & 4 ? b2 : ~b2);
                M &= (lane & 8 ? b3 : ~b3);
                M &= (lane & 16 ? b4 : ~b4);
                M &= (lane & 32 ? b5 : ~b5);
                C0 += (uint32_t)__popcll(M & ~b6 & ~b7);
                C1 += (uint32_t)__popcll(M &  b6 & ~b7);
                C2 += (uint32_t)__popcll(M & ~b6 &  b7);
                C3 += (uint32_t)__popcll(M &  b6 &  b7);
                d = dn;
            }
        }
        sm.whist[(wave << 8) + lane]       = C0;
        sm.whist[(wave << 8) + 64 + lane]  = C1;
        sm.whist[(wave << 8) + 128 + lane] = C2;
        sm.whist[(wave << 8) + 192 + lane] = C3;
        __syncthreads();

        // ---------- Block scan: whist -> (wave,digit) start offsets ----------
        uint32_t run = 0u, inc = 0u;
        if (tid < 256) {
#pragma unroll
            for (int w = 0; w < WAVES; ++w) run += sm.whist[(w << 8) + tid];
            inc = run;
#pragma unroll
            for (int dlt = 1; dlt < 64; dlt <<= 1) {
                uint32_t t = __shfl_up(inc, dlt, 64);
                if (lane >= dlt) inc += t;
            }
            if (lane == 63) sm.wtot[tid >> 6] = inc;
        }
        __syncthreads();
        if (tid < 256) {
            uint32_t base = 0u;
#pragma unroll
            for (int k = 0; k < 4; ++k) if (k < (tid >> 6)) base += sm.wtot[k];
            uint32_t excl = base + inc - run;
#pragma unroll
            for (int w = 0; w < WAVES; ++w) {
                uint32_t t = sm.whist[(w << 8) + tid];
                sm.whist[(w << 8) + tid] = excl;
                excl += t;
            }
        }
        __syncthreads();

        // ---------- Phase B: barrier-free, atomic-free scatter ----------
        C0 = sm.whist[(wave << 8) + lane];
        C1 = sm.whist[(wave << 8) + 64 + lane];
        C2 = sm.whist[(wave << 8) + 128 + lane];
        C3 = sm.whist[(wave << 8) + 192 + lane];

        auto loadE = [&](int it) -> ELEM {
            const int gi = wave * SEG + it * 64 + lane;
            if (p == 0) {
                float cv = rawRow[gi];
                uint32_t k = fkey(cv);
                if constexpr (IS_SRC) {
                    float sv = raw2Row[gi];
                    uint64_t e = (((uint64_t)(k >> 7)) << 16) | (uint32_t)gi;
                    if (cv < 0.f) e |= 1ull << 48;
                    if (sv < 0.f) e |= 1ull << 49;
                    return e;
                } else {
                    return (ELEM)k;
                }
            }
            const ELEM* inb = (const ELEM*)((p == 1) ? (void*)A : (void*)B);
            return inb[gi];
        };
        ELEM* outb = (p == 0) ? A : B;

        ELEM v = loadE(0);
        for (int it = 0; it < ITERS; ++it) {
            ELEM vn = (ELEM)0;
            if (it + 1 < ITERS) vn = loadE(it + 1);   // prefetch

            uint32_t d;
            if constexpr (IS_SRC) d = (uint32_t)(v >> (16 + 8 * p)) & 255u;
            else                  d = (((uint32_t)v >> 7) >> (8 * p)) & 255u;

            const uint64_t b0 = __ballot(d & 1u),  b1 = __ballot(d & 2u);
            const uint64_t b2 = __ballot(d & 4u),  b3 = __ballot(d & 8u);
            const uint64_t b4 = __ballot(d & 16u), b5 = __ballot(d & 32u);
            const uint64_t b6 = __ballot(d & 64u), b7 = __ballot(d & 128u);

            // my peer mask -> rank within group
            uint64_t m = (d & 1u ? b0 : ~b0);
            m &= (d & 2u ? b1 : ~b1);
            m &= (d & 4u ? b2 : ~b2);
            m &= (d & 8u ? b3 : ~b3);
            m &= (d & 16u ? b4 : ~b4);
            m &= (d & 32u ? b5 : ~b5);
            m &= (d & 64u ? b6 : ~b6);
            m &= (d & 128u ? b7 : ~b7);
            const uint32_t rw = (uint32_t)__popcll(m & lane_lt);

            // running base for my digit, fetched from its owner lane
            const int sl = (int)(d & 63u);
            const uint32_t g0 = (uint32_t)__shfl((int)C0, sl, 64);
            const uint32_t g1 = (uint32_t)__shfl((int)C1, sl, 64);
            const uint32_t g2 = (uint32_t)__shfl((int)C2, sl, 64);
            const uint32_t g3 = (uint32_t)__shfl((int)C3, sl, 64);
            const uint32_t base = (d & 64u) ? ((d & 128u) ? g3 : g1)
                                            : ((d & 128u) ? g2 : g0);
            const uint32_t off = base + rw;

            if (p < 2) {
                outb[off] = v;
            } else {
                if constexpr (IS_SRC)
                    rowF[off] = (uint32_t)(v & 0xFFFFull) |
                                (((uint32_t)(v >> 48)) << 16);
                else
                    rowF[off] = (uint32_t)v;   // exact |style| bits
            }

            // owned-counter updates (digit 64k+lane lives in lane, reg Ck)
            uint64_t M = (lane & 1 ? b0 : ~b0);
            M &= (lane & 2 ? b1 : ~b1);
            M &= (lane & 4 ? b2 : ~b2);
            M &= (lane & 8 ? b3 : ~b3);
            M &= (lane & 16 ? b4 : ~b4);
            M &= (lane & 32 ? b5 : ~b5);
            C0 += (uint32_t)__popcll(M & ~b6 & ~b7);
            C1 += (uint32_t)__popcll(M &  b6 & ~b7);
            C2 += (uint32_t)__popcll(M & ~b6 &  b7);
            C3 += (uint32_t)__popcll(M &  b6 &  b7);
            v = vn;
        }
        __syncthreads(); // seal this pass's global writes before next phase A
    }
}

__device__ __forceinline__ float detail_one(float c, float s) {
    const float f = (c < 0.f) ? ((s < 0.f) ? -1.f : COS_04PI)
                              : ((s < 0.f) ? -COS_04PI : 1.f);
    return (0.4f * fabsf(c) + 0.6f * fabsf(s)) * f;
}

} // namespace

__global__ __launch_bounds__(ST, 8)
void sort_merged3(const float* __restrict__ ca, const float* __restrict__ sa,
                  void* srcA, void* srcB, void* tgtA, void* tgtB)
{
    __shared__ SortSmem sm;
    const int b = blockIdx.x;
    const int row = b >> 1;
    if ((b & 1) == 0) {
        uint32_t* rowF = (uint32_t*)((uint64_t*)srcA + (size_t)row * ROW_N);
        sort_row<true>(sm, ca, sa, srcA, srcB, rowF, row);
    } else {
        uint32_t* rowF = (uint32_t*)tgtA + (size_t)row * ROW_N;
        sort_row<false>(sm, sa, nullptr, tgtA, tgtB, rowF, row);
    }
}

// out0[row, idx] = t_sorted[row, k] * cos(0.8*ph(c) + 0.2*ph(s))
// srcF rows at stride 131072 u32 (first half of each row's u64 A slice);
// tgtF is flat [ROWS][ROW_N] u32.
__global__ __launch_bounds__(256)
void approx_finalize(const uint32_t* __restrict__ srcF,
                     const uint32_t* __restrict__ tgtF,
                     float* __restrict__ out0)
{
    const size_t kk = (size_t)blockIdx.x * blockDim.x + threadIdx.x;
    const size_t row = kk >> 16;
    const uint32_t kl = (uint32_t)(kk & 65535u);
    const uint32_t v = srcF[(row << 17) | kl];
    const size_t j = (row << 16) | (v & 0xFFFFu);
    const float t = __uint_as_float(tgtF[kk]);
    const uint32_t cneg = (v >> 16) & 1u;
    const uint32_t sneg = (v >> 17) & 1u;
    const float f = cneg ? (sneg ? -1.f : -COS_02PI)
                         : (sneg ? COS_02PI : 1.f);
    out0[j] = t * f;
}

__global__ __launch_bounds__(256)
void details_kernel(const float4* __restrict__ ch, const float4* __restrict__ sh,
                    const float4* __restrict__ cv, const float4* __restrict__ sv,
                    const float4* __restrict__ cd, const float4* __restrict__ sd,
                    float4* __restrict__ oh, float4* __restrict__ ov,
                    float4* __restrict__ od)
{
    const size_t i = (size_t)blockIdx.x * blockDim.x + threadIdx.x;
    float4 a, b, r;
    a = ch[i]; b = sh[i];
    r.x = detail_one(a.x, b.x); r.y = detail_one(a.y, b.y);
    r.z = detail_one(a.z, b.z); r.w = detail_one(a.w, b.w);
    oh[i] = r;
    a = cv[i]; b = sv[i];
    r.x = detail_one(a.x, b.x); r.y = detail_one(a.y, b.y);
    r.z = detail_one(a.z, b.z); r.w = detail_one(a.w, b.w);
    ov[i] = r;
    a = cd[i]; b = sd[i];
    r.x = detail_one(a.x, b.x); r.y = detail_one(a.y, b.y);
    r.z = detail_one(a.z, b.z); r.w = detail_one(a.w, b.w);
    od[i] = r;
}

extern "C" void kernel_launch(void* const* d_in, const int* in_sizes, int n_in,
                              void* d_out, int out_size, void* d_ws, size_t ws_size,
                              hipStream_t stream)
{
    (void)in_sizes; (void)n_in; (void)out_size; (void)ws_size;
    const float* ca = (const float*)d_in[0];
    const float* ch = (const float*)d_in[1];
    const float* cv = (const float*)d_in[2];
    const float* cd = (const float*)d_in[3];
    const float* sa = (const float*)d_in[4];
    const float* sh = (const float*)d_in[5];
    const float* sv = (const float*)d_in[6];
    const float* sd = (const float*)d_in[7];

    float* out = (float*)d_out;
    float* out_a = out;
    float* out_h = out + NTOT;
    float* out_v = out + 2 * NTOT;
    float* out_d = out + 3 * NTOT;

    // Scratch:
    //  srcA: ws[0,134MB) u64 ping; pass2 writes compact u32 into each row's
    //        own retired A slice (stride 131072 u32 per row)
    //  tgtA: ws[134,201MB) u32 ping; pass2 overwrites own slice (flat u32)
    //  srcB: out_h..out_v (134MB u64 pong), tgtB: out_d (67MB u32 pong)
    // finalize reads ws only; details then freely overwrites out_h/v/d.
    uint64_t* srcA = (uint64_t*)d_ws;
    uint64_t* srcB = (uint64_t*)out_h;
    uint32_t* tgtA = (uint32_t*)((char*)d_ws + NTOT * 8);
    uint32_t* tgtB = (uint32_t*)out_d;

    sort_merged3<<<2 * ROWS, ST, 0, stream>>>(ca, sa, srcA, srcB, tgtA, tgtB);

    approx_finalize<<<(int)(NTOT / 256), 256, 0, stream>>>(
        (const uint32_t*)srcA, (const uint32_t*)tgtA, out_a);

    details_kernel<<<(int)(NTOT / 4 / 256), 256, 0, stream>>>(
        (const float4*)ch, (const float4*)sh,
        (const float4*)cv, (const float4*)sv,
        (const float4*)cd, (const float4*)sd,
        (float4*)out_h, (float4*)out_v, (float4*)out_d);
}

// Round 5
// 696.224 us; speedup vs baseline: 2.3652x; 2.3652x over previous
//
#include <hip/hip_runtime.h>
#include <cstdint>
#include <type_traits>

namespace {

constexpr int ROWS = 256;            // B*C
constexpr int ROW_N = 65536;         // H*W
constexpr int ST = 1024;             // threads per sort block (16 waves)
constexpr int CHUNK = 2048;          // elements per block-wide chunk
constexpr int NCHUNK = ROW_N / CHUNK;  // 32
constexpr int SUBS = 32;             // 2 halves x 16 waves (position-ordered)
constexpr size_t NTOT = (size_t)ROWS * ROW_N;

constexpr float COS_02PI = 0.80901699437494745f;  // cos(0.2*pi)
constexpr float COS_04PI = 0.30901699437494745f;  // cos(0.4*pi)

struct SortSmem {
    __align__(16) uint32_t whist[SUBS * 256];  // 32 KB max (8-bit pass)
    __align__(16) char stage[CHUNK * 8];       // 16 KB digit-ordered stage
    __align__(16) uint32_t hist[256];          // next-pass histogram
    uint32_t sbase[2][256];                    // running global digit base (ping-pong)
    uint32_t lstartP[2][256];                  // chunk-local digit starts (ping-pong)
    uint32_t wavesum[4];
};

__device__ __forceinline__ uint32_t fkey(float x) {
    return __float_as_uint(fabsf(x));  // monotone for non-negative floats
}

__device__ void prepass_hist(SortSmem& sm, const float* __restrict__ rawA)
{
    // pass-0 digit histogram: digit = (fkey>>10)&255 (mantissa bits, ~uniform)
    const int tid = threadIdx.x;
    const float4* r4 = (const float4*)rawA;
#pragma unroll 4
    for (int i = 0; i < ROW_N / 4 / ST; ++i) {   // 16
        float4 f = r4[i * ST + tid];
        atomicAdd(&sm.hist[(fkey(f.x) >> 10) & 255u], 1u);
        atomicAdd(&sm.hist[(fkey(f.y) >> 10) & 255u], 1u);
        atomicAdd(&sm.hist[(fkey(f.z) >> 10) & 255u], 1u);
        atomicAdd(&sm.hist[(fkey(f.w) >> 10) & 255u], 1u);
    }
    __syncthreads();
}

// One stable radix pass over a row. Key = top-22 bits of |x|.
// src payloads: P0/P1 u64 = k22<<18 | sneg<<17 | cneg<<16 | idx16 ; P2 in u32
//   = k22_hi14<<18 | signs | idx. tgt payloads: full |x| bits u32 throughout.
// Chunk pipeline: ballot-rank -> LDS digit-ordered stage -> coalesced copy-out.
template <bool IS_SRC, int P>
__device__ void run_pass(SortSmem& sm, const float* __restrict__ rawA,
                         const float* __restrict__ rawS,
                         const void* __restrict__ inBuf,
                         void* __restrict__ outBuf)
{
    using EIN  = std::conditional_t<IS_SRC && (P < 2), uint64_t, uint32_t>;
    using EOUT = std::conditional_t<IS_SRC && (P == 0), uint64_t, uint32_t>;
    constexpr int DSH = IS_SRC ? (P == 0 ? 18 : P == 1 ? 26 : 25)
                               : (P == 0 ? 10 : P == 1 ? 18 : 25);
    constexpr int DBITS = (P == 0) ? 8 : 7;
    constexpr int ND = 1 << DBITS;
    constexpr int NSH = IS_SRC ? (P == 0 ? 26 : 33) : (P == 0 ? 18 : 25);

    const int tid = threadIdx.x;
    const int lane = tid & 63;
    const int wave = tid >> 6;
    const uint64_t lane_lt = (1ull << lane) - 1ull;
    EIN* stg = (EIN*)sm.stage;

    // ---- pass start: seed sbase[0] from hist (exclusive scan), zero hist ----
    {
        uint32_t h = 0u, incl = 0u;
        if (tid < ND) {
            h = sm.hist[tid];
            sm.hist[tid] = 0u;   // ready for next pass's accumulation
            incl = h;
#pragma unroll
            for (int dd = 1; dd < 64; dd <<= 1) {
                uint32_t t = __shfl_up(incl, dd, 64);
                if (lane >= dd) incl += t;
            }
            if (lane == 63) sm.wavesum[tid >> 6] = incl;
        }
        __syncthreads();
        if (tid < ND) {
            uint32_t woff = 0u;
#pragma unroll
            for (int j = 0; j < ND / 64; ++j)
                if (j < (tid >> 6)) woff += sm.wavesum[j];
            sm.sbase[0][tid] = woff + incl - h;
        }
        __syncthreads();
    }

    auto loadE = [&](int c, int h) -> EIN {
        const int pos = c * CHUNK + (h << 10) + (wave << 6) + lane;
        if constexpr (P == 0) {
            float av = rawA[pos];
            uint32_t k = fkey(av);
            if constexpr (IS_SRC) {
                float sv = rawS[pos];
                uint64_t e = (((uint64_t)(k >> 10)) << 18) | (uint32_t)pos;
                if (av < 0.f) e |= 1ull << 16;   // cneg -> bit16
                if (sv < 0.f) e |= 1ull << 17;   // sneg -> bit17
                return e;
            } else {
                return k;
            }
        } else {
            return ((const EIN*)inBuf)[pos];
        }
    };

    EIN v0 = loadE(0, 0), v1 = loadE(0, 1);

    for (int c = 0; c < NCHUNK; ++c) {
        const int par = c & 1;

        // ---- rank phase: self-zero own whist rows, ballot-rank both halves ----
        {
            uint4 z = make_uint4(0u, 0u, 0u, 0u);
            for (int z4 = lane; z4 < ND / 4; z4 += 64) {
                ((uint4*)&sm.whist[wave * ND])[z4] = z;          // h=0 row
                ((uint4*)&sm.whist[(16 + wave) * ND])[z4] = z;   // h=1 row
            }
        }
        uint32_t d0, rw0, d1, rw1;
        {
            d0 = (uint32_t)(v0 >> DSH) & (ND - 1);
            uint64_t m = ~0ull;
#pragma unroll
            for (int b = 0; b < DBITS; ++b) {
                uint64_t bal = __ballot((d0 >> b) & 1u);
                m &= ((d0 >> b) & 1u) ? bal : ~bal;
            }
            rw0 = (uint32_t)__popcll(m & lane_lt);
            if (rw0 == 0u) sm.whist[wave * ND + d0] = (uint32_t)__popcll(m);
        }
        {
            d1 = (uint32_t)(v1 >> DSH) & (ND - 1);
            uint64_t m = ~0ull;
#pragma unroll
            for (int b = 0; b < DBITS; ++b) {
                uint64_t bal = __ballot((d1 >> b) & 1u);
                m &= ((d1 >> b) & 1u) ? bal : ~bal;
            }
            rw1 = (uint32_t)__popcll(m & lane_lt);
            if (rw1 == 0u) sm.whist[(16 + wave) * ND + d1] = (uint32_t)__popcll(m);
        }
        // fused histogram for next pass
        if constexpr (P == 0) {
            // next digit = mantissa-ish bits: ~uniform -> plain atomics
            atomicAdd(&sm.hist[(uint32_t)(v0 >> NSH) & 127u], 1u);
            atomicAdd(&sm.hist[(uint32_t)(v1 >> NSH) & 127u], 1u);
        } else if constexpr (P == 1) {
            // next digit = exponent bits: skewed -> leader-aggregated
#pragma unroll
            for (int h = 0; h < 2; ++h) {
                uint32_t nd = (uint32_t)((h ? v1 : v0) >> NSH) & 127u;
                uint64_t m = ~0ull;
#pragma unroll
                for (int b = 0; b < 7; ++b) {
                    uint64_t bal = __ballot((nd >> b) & 1u);
                    m &= ((nd >> b) & 1u) ? bal : ~bal;
                }
                if ((m & lane_lt) == 0ull)
                    atomicAdd(&sm.hist[nd], (uint32_t)__popcll(m));
            }
        }
        __syncthreads();  // b1: whist counts complete

        // ---- scan A: per-digit totals + wave-level inclusive scan ----
        uint32_t tot = 0u, incl = 0u;
        if (tid < ND) {
#pragma unroll
            for (int i = 0; i < SUBS; ++i) tot += sm.whist[i * ND + tid];
            incl = tot;
#pragma unroll
            for (int dd = 1; dd < 64; dd <<= 1) {
                uint32_t t = __shfl_up(incl, dd, 64);
                if (lane >= dd) incl += t;
            }
            if (lane == 63) sm.wavesum[tid >> 6] = incl;
        }
        __syncthreads();  // b1.5

        // ---- scan B: chunk-local digit starts; rewrite whist as local prefixes ----
        if (tid < ND) {
            uint32_t woff = 0u;
#pragma unroll
            for (int j = 0; j < ND / 64; ++j)
                if (j < (tid >> 6)) woff += sm.wavesum[j];
            uint32_t ls = woff + incl - tot;
            sm.lstartP[par][tid] = ls;
            uint32_t run = ls;
#pragma unroll
            for (int i = 0; i < SUBS; ++i) {
                uint32_t t = sm.whist[i * ND + tid];
                sm.whist[i * ND + tid] = run;
                run += t;
            }
            sm.sbase[par ^ 1][tid] = sm.sbase[par][tid] + (run - ls);
        }
        __syncthreads();  // b2: local offsets ready

        // ---- LDS stage scatter + global prefetch for next chunk ----
        stg[sm.whist[wave * ND + d0] + rw0] = v0;
        stg[sm.whist[(16 + wave) * ND + d1] + rw1] = v1;
        EIN n0 = (EIN)0, n1 = (EIN)0;
        if (c + 1 < NCHUNK) { n0 = loadE(c + 1, 0); n1 = loadE(c + 1, 1); }
        __syncthreads();  // b3: stage complete

        // ---- coalesced copy-out: slot i -> sbase[d] + i - lstart[d] ----
#pragma unroll
        for (int h = 0; h < 2; ++h) {
            const int slot = tid + (h << 10);
            EIN u = stg[slot];
            uint32_t d = (uint32_t)(u >> DSH) & (ND - 1);
            uint32_t go = sm.sbase[par][d] + (uint32_t)slot - sm.lstartP[par][d];
            EOUT ov;
            if constexpr (IS_SRC && P == 1)
                ov = (uint32_t)(((u >> 26) << 18) | (u & 0x3FFFFull));
            else if constexpr (IS_SRC && P == 2)
                ov = (uint32_t)(u & 0x3FFFFu);
            else
                ov = (EOUT)u;
            ((EOUT*)outBuf)[go] = ov;
        }
        v0 = n0; v1 = n1;
    }
    __syncthreads();  // seal pass: global writes drained before next pass reads
}

__device__ __forceinline__ float detail_one(float c, float s) {
    const float f = (c < 0.f) ? ((s < 0.f) ? -1.f : COS_04PI)
                              : ((s < 0.f) ? -COS_04PI : 1.f);
    return (0.4f * fabsf(c) + 0.6f * fabsf(s)) * f;
}

} // namespace

__global__ __launch_bounds__(ST, 4)
void sort_kernel(const float* __restrict__ ca, const float* __restrict__ sa,
                 uint64_t* srcA, uint32_t* srcB32,
                 uint32_t* tgtA, uint32_t* tgtB, uint32_t* tgtF)
{
    __shared__ SortSmem sm;
    const int row = blockIdx.x >> 1;
    if (threadIdx.x < 256) sm.hist[threadIdx.x] = 0u;
    __syncthreads();

    if ((blockIdx.x & 1) == 0) {
        const float* cRow = ca + (size_t)row * ROW_N;
        const float* sRow = sa + (size_t)row * ROW_N;
        uint64_t* A = srcA + (size_t)row * ROW_N;
        uint32_t* B = srcB32 + (size_t)row * ROW_N;
        uint32_t* F = (uint32_t*)A;  // row's own retired slice (stride 2^17 u32)
        prepass_hist(sm, cRow);
        run_pass<true, 0>(sm, cRow, sRow, nullptr, A);
        run_pass<true, 1>(sm, nullptr, nullptr, A, B);
        run_pass<true, 2>(sm, nullptr, nullptr, B, F);
    } else {
        const float* sRow = sa + (size_t)row * ROW_N;
        uint32_t* A = tgtA + (size_t)row * ROW_N;
        uint32_t* B = tgtB + (size_t)row * ROW_N;
        uint32_t* F = tgtF + (size_t)row * ROW_N;
        prepass_hist(sm, sRow);
        run_pass<false, 0>(sm, sRow, nullptr, nullptr, A);
        run_pass<false, 1>(sm, nullptr, nullptr, A, B);
        run_pass<false, 2>(sm, nullptr, nullptr, B, F);
    }
}

// out0[row, idx] = t_sorted[row, k] * cos(0.8*ph(c) + 0.2*ph(s))
// srcF rows at stride 2^17 u32 (first half of each row's u64 A slice);
// tgtF is flat [ROWS][ROW_N] u32 (exact |style| float bits, sorted).
__global__ __launch_bounds__(256)
void approx_finalize(const uint32_t* __restrict__ srcF,
                     const uint32_t* __restrict__ tgtF,
                     float* __restrict__ out0)
{
    const size_t kk = (size_t)blockIdx.x * blockDim.x + threadIdx.x;
    const size_t row = kk >> 16;
    const uint32_t kl = (uint32_t)(kk & 65535u);
    const uint32_t v = srcF[(row << 17) | kl];
    const size_t j = (row << 16) | (v & 0xFFFFu);
    const float t = __uint_as_float(tgtF[kk]);
    const uint32_t cneg = (v >> 16) & 1u;
    const uint32_t sneg = (v >> 17) & 1u;
    const float f = cneg ? (sneg ? -1.f : -COS_02PI)
                         : (sneg ? COS_02PI : 1.f);
    out0[j] = t * f;
}

__global__ __launch_bounds__(256)
void details_kernel(const float4* __restrict__ ch, const float4* __restrict__ sh,
                    const float4* __restrict__ cv, const float4* __restrict__ sv,
                    const float4* __restrict__ cd, const float4* __restrict__ sd,
                    float4* __restrict__ oh, float4* __restrict__ ov,
                    float4* __restrict__ od)
{
    const size_t i = (size_t)blockIdx.x * blockDim.x + threadIdx.x;
    float4 a, b, r;
    a = ch[i]; b = sh[i];
    r.x = detail_one(a.x, b.x); r.y = detail_one(a.y, b.y);
    r.z = detail_one(a.z, b.z); r.w = detail_one(a.w, b.w);
    oh[i] = r;
    a = cv[i]; b = sv[i];
    r.x = detail_one(a.x, b.x); r.y = detail_one(a.y, b.y);
    r.z = detail_one(a.z, b.z); r.w = detail_one(a.w, b.w);
    ov[i] = r;
    a = cd[i]; b = sd[i];
    r.x = detail_one(a.x, b.x); r.y = detail_one(a.y, b.y);
    r.z = detail_one(a.z, b.z); r.w = detail_one(a.w, b.w);
    od[i] = r;
}

extern "C" void kernel_launch(void* const* d_in, const int* in_sizes, int n_in,
                              void* d_out, int out_size, void* d_ws, size_t ws_size,
                              hipStream_t stream)
{
    (void)in_sizes; (void)n_in; (void)out_size; (void)ws_size;
    const float* ca = (const float*)d_in[0];
    const float* ch = (const float*)d_in[1];
    const float* cv = (const float*)d_in[2];
    const float* cd = (const float*)d_in[3];
    const float* sa = (const float*)d_in[4];
    const float* sh = (const float*)d_in[5];
    const float* sv = (const float*)d_in[6];
    const float* sd = (const float*)d_in[7];

    float* out = (float*)d_out;
    float* out_a = out;
    float* out_h = out + NTOT;
    float* out_v = out + 2 * NTOT;
    float* out_d = out + 3 * NTOT;

    // Buffers (ws >= 201 MB, proven by prior rounds):
    //  src: P0 -> srcA u64 (ws[0,134MB));  P1: srcA -> srcB32 u32 (ws[134,201));
    //       P2: srcB32 -> compact u32 into row's own retired srcA slice (srcF).
    //  tgt (u32 all passes): P0 -> out_d slice; P1 -> out_h; P2 -> out_v (tgtF).
    //  finalize reads srcF (ws) + tgtF (out_v) BEFORE details overwrites h/v/d.
    uint64_t* srcA = (uint64_t*)d_ws;
    uint32_t* srcB32 = (uint32_t*)((char*)d_ws + NTOT * 8);
    uint32_t* tgtA = (uint32_t*)out_d;
    uint32_t* tgtB = (uint32_t*)out_h;
    uint32_t* tgtF = (uint32_t*)out_v;

    sort_kernel<<<2 * ROWS, ST, 0, stream>>>(ca, sa, srcA, srcB32, tgtA, tgtB, tgtF);

    approx_finalize<<<(int)(NTOT / 256), 256, 0, stream>>>(
        (const uint32_t*)d_ws, (const uint32_t*)tgtF, out_a);

    details_kernel<<<(int)(NTOT / 4 / 256), 256, 0, stream>>>(
        (const float4*)ch, (const float4*)sh,
        (const float4*)cv, (const float4*)sv,
        (const float4*)cd, (const float4*)sd,
        (float4*)out_h, (float4*)out_v, (float4*)out_d);
}

// Round 6
// 650.304 us; speedup vs baseline: 2.5322x; 1.0706x over previous
//
#include <hip/hip_runtime.h>
#include <cstdint>

namespace {

constexpr int ROWS = 256;            // B*C
constexpr int ROW_N = 65536;         // H*W
constexpr int ST = 1024;             // threads per sort block (16 waves)
constexpr int CHUNK = 2048;          // elements per block-wide chunk
constexpr int NCHUNK = ROW_N / CHUNK;  // 32
constexpr int SUBS = 32;             // 2 halves x 16 waves (position-ordered)
constexpr size_t NTOT = (size_t)ROWS * ROW_N;

constexpr float COS_02PI = 0.80901699437494745f;  // cos(0.2*pi)
constexpr float COS_04PI = 0.30901699437494745f;  // cos(0.4*pi)

struct SortSmem {
    __align__(16) uint32_t whist[SUBS * 256];  // 32 KB (8-bit pass max)
    __align__(16) uint32_t stage[CHUNK];       // 8 KB digit-ordered stage (u32)
    __align__(16) uint8_t  dstg[CHUNK];        // 2 KB digit-per-slot (src P0 only)
    __align__(16) uint32_t hist[256];          // next-pass histogram
    uint32_t sbase[2][256];                    // running global digit base (ping-pong)
    uint32_t adj[2][256];                      // sbase - lstart, per parity
    uint32_t wavesum[4];
};

__device__ __forceinline__ uint32_t fkey(float x) {
    return __float_as_uint(fabsf(x));  // monotone for non-negative floats
}

__device__ void prepass_hist(SortSmem& sm, const float* __restrict__ rawA)
{
    // pass-0 digit histogram: digit = (fkey>>10)&255 (mantissa bits, ~uniform)
    const int tid = threadIdx.x;
    const float4* r4 = (const float4*)rawA;
#pragma unroll 4
    for (int i = 0; i < ROW_N / 4 / ST; ++i) {   // 16
        float4 f = r4[i * ST + tid];
        atomicAdd(&sm.hist[(fkey(f.x) >> 10) & 255u], 1u);
        atomicAdd(&sm.hist[(fkey(f.y) >> 10) & 255u], 1u);
        atomicAdd(&sm.hist[(fkey(f.z) >> 10) & 255u], 1u);
        atomicAdd(&sm.hist[(fkey(f.w) >> 10) & 255u], 1u);
    }
    __syncthreads();
}

// One stable radix pass. Key = bits [31:10] of |x| (22 bits, bit31 always 0).
// Digit plan (both sorts): P0 bits 10-17 (8b), P1 bits 18-24 (7b), P2 bits 25-31 (7b).
// ALL buffers u32. src element after P0: fkey[31:18]<<18 | sneg<<17 | cneg<<16 | idx16.
// tgt element: full |x| bits throughout.
// Chunk pipeline: ballot-rank -> LDS digit-ordered stage -> coalesced copy-out.
template <bool IS_SRC, int P>
__device__ void run_pass(SortSmem& sm, const float* __restrict__ rawA,
                         const float* __restrict__ rawS,
                         const uint32_t* __restrict__ inBuf,
                         uint32_t* __restrict__ outBuf)
{
    constexpr int DBITS = (P == 0) ? 8 : 7;
    constexpr int ND = 1 << DBITS;
    constexpr int DSH = (P == 0) ? 10 : (P == 1 ? 18 : 25);  // digit shift in staged val
    constexpr bool P0SRC = IS_SRC && (P == 0);

    const int tid = threadIdx.x;
    const int lane = tid & 63;
    const int wave = tid >> 6;
    const uint64_t lane_lt = (1ull << lane) - 1ull;

    // ---- pass start: sbase[0] = exclusive scan of hist; zero hist for reuse ----
    {
        uint32_t h = 0u, incl = 0u;
        if (tid < ND) {
            h = sm.hist[tid];
            sm.hist[tid] = 0u;
            incl = h;
#pragma unroll
            for (int dd = 1; dd < 64; dd <<= 1) {
                uint32_t t = __shfl_up(incl, dd, 64);
                if (lane >= dd) incl += t;
            }
            if (lane == 63) sm.wavesum[tid >> 6] = incl;
        }
        __syncthreads();
        if (tid < ND) {
            uint32_t woff = 0u;
#pragma unroll
            for (int j = 0; j < ND / 64; ++j)
                if (j < (tid >> 6)) woff += sm.wavesum[j];
            sm.sbase[0][tid] = woff + incl - h;
        }
        __syncthreads();
    }

    // returns (digit<<32)|value
    auto loadE = [&](int c, int h) -> uint64_t {
        const int pos = c * CHUNK + (h << 10) + (wave << 6) + lane;
        if constexpr (P == 0) {
            float av = rawA[pos];
            uint32_t k = fkey(av);
            if constexpr (IS_SRC) {
                float sv = rawS[pos];
                uint32_t o = ((k >> 18) << 18) | (uint32_t)pos;
                if (av < 0.f) o |= 1u << 16;
                if (sv < 0.f) o |= 1u << 17;
                return (((uint64_t)((k >> 10) & 255u)) << 32) | o;
            } else {
                return (((uint64_t)((k >> 10) & 255u)) << 32) | k;
            }
        } else {
            uint32_t v = inBuf[pos];
            return (((uint64_t)((v >> DSH) & (ND - 1))) << 32) | v;
        }
    };

    uint64_t e0 = loadE(0, 0), e1 = loadE(0, 1);

    for (int c = 0; c < NCHUNK; ++c) {
        const int par = c & 1;

        // ---- rank phase: self-zero own whist rows, ballot-rank both halves ----
        {
            uint4 z = make_uint4(0u, 0u, 0u, 0u);
            for (int z4 = lane; z4 < ND / 4; z4 += 64) {
                ((uint4*)&sm.whist[wave * ND])[z4] = z;          // h=0 row
                ((uint4*)&sm.whist[(16 + wave) * ND])[z4] = z;   // h=1 row
            }
        }
        const uint32_t d0 = (uint32_t)(e0 >> 32), v0 = (uint32_t)e0;
        const uint32_t d1 = (uint32_t)(e1 >> 32), v1 = (uint32_t)e1;
        uint32_t rw0, rw1;
        {
            uint64_t m = ~0ull;
#pragma unroll
            for (int b = 0; b < DBITS; ++b) {
                uint64_t bal = __ballot((d0 >> b) & 1u);
                m &= ((d0 >> b) & 1u) ? bal : ~bal;
            }
            rw0 = (uint32_t)__popcll(m & lane_lt);
            if (rw0 == 0u) sm.whist[wave * ND + d0] = (uint32_t)__popcll(m);
        }
        {
            uint64_t m = ~0ull;
#pragma unroll
            for (int b = 0; b < DBITS; ++b) {
                uint64_t bal = __ballot((d1 >> b) & 1u);
                m &= ((d1 >> b) & 1u) ? bal : ~bal;
            }
            rw1 = (uint32_t)__popcll(m & lane_lt);
            if (rw1 == 0u) sm.whist[(16 + wave) * ND + d1] = (uint32_t)__popcll(m);
        }
        // fused histogram for next pass
        if constexpr (P == 0) {
            // next digit = bits 18-24 (mostly mantissa): mild contention -> plain atomics
            atomicAdd(&sm.hist[(v0 >> 18) & 127u], 1u);
            atomicAdd(&sm.hist[(v1 >> 18) & 127u], 1u);
        } else if constexpr (P == 1) {
            // next digit = exponent bits 25-31: skewed -> leader-aggregated
#pragma unroll
            for (int h = 0; h < 2; ++h) {
                uint32_t nd = ((h ? v1 : v0) >> 25) & 127u;
                uint64_t m = ~0ull;
#pragma unroll
                for (int b = 0; b < 7; ++b) {
                    uint64_t bal = __ballot((nd >> b) & 1u);
                    m &= ((nd >> b) & 1u) ? bal : ~bal;
                }
                if ((m & lane_lt) == 0ull)
                    atomicAdd(&sm.hist[nd], (uint32_t)__popcll(m));
            }
        }
        __syncthreads();  // b1: whist counts complete

        // ---- scan A: per-digit totals + wave-level inclusive scan ----
        uint32_t tot = 0u, incl = 0u;
        if (tid < ND) {
#pragma unroll
            for (int i = 0; i < SUBS; ++i) tot += sm.whist[i * ND + tid];
            incl = tot;
#pragma unroll
            for (int dd = 1; dd < 64; dd <<= 1) {
                uint32_t t = __shfl_up(incl, dd, 64);
                if (lane >= dd) incl += t;
            }
            if (lane == 63) sm.wavesum[tid >> 6] = incl;
        }
        __syncthreads();  // b1.5

        // ---- scan B: local starts -> whist local prefixes; adj & next sbase ----
        if (tid < ND) {
            uint32_t woff = 0u;
#pragma unroll
            for (int j = 0; j < ND / 64; ++j)
                if (j < (tid >> 6)) woff += sm.wavesum[j];
            const uint32_t ls = woff + incl - tot;
            uint32_t run = ls;
#pragma unroll
            for (int i = 0; i < SUBS; ++i) {
                uint32_t t = sm.whist[i * ND + tid];
                sm.whist[i * ND + tid] = run;
                run += t;
            }
            const uint32_t sb = sm.sbase[par][tid];
            sm.adj[par][tid] = sb - ls;
            sm.sbase[par ^ 1][tid] = sb + (run - ls);
        }
        __syncthreads();  // b2: local offsets ready

        // ---- LDS stage scatter + global prefetch for next chunk ----
        {
            const uint32_t s0 = sm.whist[wave * ND + d0] + rw0;
            sm.stage[s0] = v0;
            if constexpr (P0SRC) sm.dstg[s0] = (uint8_t)d0;
            const uint32_t s1 = sm.whist[(16 + wave) * ND + d1] + rw1;
            sm.stage[s1] = v1;
            if constexpr (P0SRC) sm.dstg[s1] = (uint8_t)d1;
        }
        uint64_t n0 = 0ull, n1 = 0ull;
        if (c + 1 < NCHUNK) { n0 = loadE(c + 1, 0); n1 = loadE(c + 1, 1); }
        __syncthreads();  // b3: stage complete

        // ---- coalesced copy-out: slot i -> adj[d] + i ----
#pragma unroll
        for (int h = 0; h < 2; ++h) {
            const int slot = tid + (h << 10);
            const uint32_t u = sm.stage[slot];
            uint32_t d;
            if constexpr (P0SRC) d = sm.dstg[slot];
            else                 d = (u >> DSH) & (ND - 1);
            const uint32_t go = sm.adj[par][d] + (uint32_t)slot;
            uint32_t ov = u;
            if constexpr (IS_SRC && P == 2) ov = u & 0x3FFFFu;  // idx+signs only
            outBuf[go] = ov;
        }
        e0 = n0; e1 = n1;
    }
    __syncthreads();  // seal pass: writes drained before next pass reads
}

__device__ __forceinline__ float detail_one(float c, float s) {
    const float f = (c < 0.f) ? ((s < 0.f) ? -1.f : COS_04PI)
                              : ((s < 0.f) ? -COS_04PI : 1.f);
    return (0.4f * fabsf(c) + 0.6f * fabsf(s)) * f;
}

} // namespace

__global__ __launch_bounds__(ST, 8)
void sort_kernel(const float* __restrict__ ca, const float* __restrict__ sa,
                 uint32_t* srcA, uint32_t* srcB,
                 uint32_t* tgtA, uint32_t* tgtB, uint32_t* tgtF)
{
    __shared__ SortSmem sm;
    const int row = blockIdx.x >> 1;
    if (threadIdx.x < 256) sm.hist[threadIdx.x] = 0u;
    __syncthreads();

    if ((blockIdx.x & 1) == 0) {
        const float* cRow = ca + (size_t)row * ROW_N;
        const float* sRow = sa + (size_t)row * ROW_N;
        uint32_t* A = srcA + (size_t)row * ROW_N;
        uint32_t* B = srcB + (size_t)row * ROW_N;
        prepass_hist(sm, cRow);
        run_pass<true, 0>(sm, cRow, sRow, nullptr, A);
        run_pass<true, 1>(sm, nullptr, nullptr, A, B);
        run_pass<true, 2>(sm, nullptr, nullptr, B, A);  // final: back into A (srcF)
    } else {
        const float* sRow = sa + (size_t)row * ROW_N;
        uint32_t* A = tgtA + (size_t)row * ROW_N;
        uint32_t* B = tgtB + (size_t)row * ROW_N;
        uint32_t* F = tgtF + (size_t)row * ROW_N;
        prepass_hist(sm, sRow);
        run_pass<false, 0>(sm, sRow, nullptr, nullptr, A);
        run_pass<false, 1>(sm, nullptr, nullptr, A, B);
        run_pass<false, 2>(sm, nullptr, nullptr, B, F);
    }
}

// out0[row, idx] = t_sorted[row, k] * cos(0.8*ph(c) + 0.2*ph(s))
// srcF flat u32 [ROWS][ROW_N]: idx16 | cneg<<16 | sneg<<17 (rank order).
// tgtF flat u32 [ROWS][ROW_N]: exact |style| float bits, sorted.
__global__ __launch_bounds__(256)
void approx_finalize(const uint32_t* __restrict__ srcF,
                     const uint32_t* __restrict__ tgtF,
                     float* __restrict__ out0)
{
    const size_t kk = (size_t)blockIdx.x * blockDim.x + threadIdx.x;
    const uint32_t v = srcF[kk];
    const size_t j = ((kk >> 16) << 16) | (v & 0xFFFFu);
    const float t = __uint_as_float(tgtF[kk]);
    const uint32_t cneg = (v >> 16) & 1u;
    const uint32_t sneg = (v >> 17) & 1u;
    const float f = cneg ? (sneg ? -1.f : -COS_02PI)
                         : (sneg ? COS_02PI : 1.f);
    out0[j] = t * f;
}

__global__ __launch_bounds__(256)
void details_kernel(const float4* __restrict__ ch, const float4* __restrict__ sh,
                    const float4* __restrict__ cv, const float4* __restrict__ sv,
                    const float4* __restrict__ cd, const float4* __restrict__ sd,
                    float4* __restrict__ oh, float4* __restrict__ ov,
                    float4* __restrict__ od)
{
    const size_t i = (size_t)blockIdx.x * blockDim.x + threadIdx.x;
    float4 a, b, r;
    a = ch[i]; b = sh[i];
    r.x = detail_one(a.x, b.x); r.y = detail_one(a.y, b.y);
    r.z = detail_one(a.z, b.z); r.w = detail_one(a.w, b.w);
    oh[i] = r;
    a = cv[i]; b = sv[i];
    r.x = detail_one(a.x, b.x); r.y = detail_one(a.y, b.y);
    r.z = detail_one(a.z, b.z); r.w = detail_one(a.w, b.w);
    ov[i] = r;
    a = cd[i]; b = sd[i];
    r.x = detail_one(a.x, b.x); r.y = detail_one(a.y, b.y);
    r.z = detail_one(a.z, b.z); r.w = detail_one(a.w, b.w);
    od[i] = r;
}

extern "C" void kernel_launch(void* const* d_in, const int* in_sizes, int n_in,
                              void* d_out, int out_size, void* d_ws, size_t ws_size,
                              hipStream_t stream)
{
    (void)in_sizes; (void)n_in; (void)out_size; (void)ws_size;
    const float* ca = (const float*)d_in[0];
    const float* ch = (const float*)d_in[1];
    const float* cv = (const float*)d_in[2];
    const float* cd = (const float*)d_in[3];
    const float* sa = (const float*)d_in[4];
    const float* sh = (const float*)d_in[5];
    const float* sv = (const float*)d_in[6];
    const float* sd = (const float*)d_in[7];

    float* out = (float*)d_out;
    float* out_a = out;
    float* out_h = out + NTOT;
    float* out_v = out + 2 * NTOT;
    float* out_d = out + 3 * NTOT;

    // Buffers (all u32; ws >= 134 MB, proven by prior rounds):
    //  src: P0 raw -> srcA (ws[0,67MB)); P1 srcA -> srcB (ws[67,134MB));
    //       P2 srcB -> srcA (= srcF, flat idx+signs in rank order).
    //  tgt: P0 -> out_d slice; P1 -> out_h slice; P2 -> out_v (tgtF, sorted keys).
    //  finalize reads srcF (ws) + tgtF (out_v) BEFORE details overwrites h/v/d.
    uint32_t* srcA = (uint32_t*)d_ws;
    uint32_t* srcB = (uint32_t*)((char*)d_ws + NTOT * 4);
    uint32_t* tgtA = (uint32_t*)out_d;
    uint32_t* tgtB = (uint32_t*)out_h;
    uint32_t* tgtF = (uint32_t*)out_v;

    sort_kernel<<<2 * ROWS, ST, 0, stream>>>(ca, sa, srcA, srcB, tgtA, tgtB, tgtF);

    approx_finalize<<<(int)(NTOT / 256), 256, 0, stream>>>(
        (const uint32_t*)srcA, (const uint32_t*)tgtF, out_a);

    details_kernel<<<(int)(NTOT / 4 / 256), 256, 0, stream>>>(
        (const float4*)ch, (const float4*)sh,
        (const float4*)cv, (const float4*)sv,
        (const float4*)cd, (const float4*)sd,
        (float4*)out_h, (float4*)out_v, (float4*)out_d);
}

// Round 7
// 626.761 us; speedup vs baseline: 2.6273x; 1.0376x over previous
//
#include <hip/hip_runtime.h>
#include <cstdint>

namespace {

constexpr int ROWS = 256;            // B*C
constexpr int ROW_N = 65536;         // H*W
constexpr int ST = 1024;             // threads per sort block (16 waves)
constexpr int CHUNK = 4096;          // elements per block-wide chunk
constexpr int NCHUNK = ROW_N / CHUNK;  // 16
constexpr int SUBS = 64;             // 4 quarters x 16 waves (position-ordered)
constexpr int EPT = 4;               // elements per thread per chunk
constexpr size_t NTOT = (size_t)ROWS * ROW_N;

constexpr float COS_02PI = 0.80901699437494745f;  // cos(0.2*pi)
constexpr float COS_04PI = 0.30901699437494745f;  // cos(0.4*pi)

struct SortSmem {
    __align__(16) uint16_t whist[SUBS * 256];  // 32 KB (8-bit pass max), u16 counts/prefixes
    __align__(16) uint32_t stage[CHUNK];       // 16 KB digit-ordered stage
    __align__(16) uint8_t  dstg[CHUNK];        // 4 KB digit-per-slot (src P0 only)
    __align__(16) uint32_t hist[256];          // next-pass histogram
    uint32_t sbase[2][256];                    // running global digit base (ping-pong)
    uint32_t adj[2][256];                      // sbase - lstart, per parity
    uint32_t wavesum[4];
};

__device__ __forceinline__ uint32_t fkey(float x) {
    return __float_as_uint(fabsf(x));  // monotone for non-negative floats
}

__device__ void prepass_hist(SortSmem& sm, const float* __restrict__ rawA)
{
    // pass-0 digit histogram: digit = (fkey>>10)&255 (mantissa bits, ~uniform)
    const int tid = threadIdx.x;
    const float4* r4 = (const float4*)rawA;
#pragma unroll 4
    for (int i = 0; i < ROW_N / 4 / ST; ++i) {   // 16
        float4 f = r4[i * ST + tid];
        atomicAdd(&sm.hist[(fkey(f.x) >> 10) & 255u], 1u);
        atomicAdd(&sm.hist[(fkey(f.y) >> 10) & 255u], 1u);
        atomicAdd(&sm.hist[(fkey(f.z) >> 10) & 255u], 1u);
        atomicAdd(&sm.hist[(fkey(f.w) >> 10) & 255u], 1u);
    }
    __syncthreads();
}

// One stable radix pass. Key = bits [31:10] of |x| (22 bits, bit31 always 0).
// Digit plan: P0 bits 10-17 (8b), P1 bits 18-24 (7b), P2 bits 25-31 (7b).
// ALL buffers u32. src element after P0: fkey[31:18]<<18 | sneg<<17 | cneg<<16 | idx16.
// tgt element: full |x| bits throughout.
// Chunk pipeline (4 elems/thread): ballot-rank -> LDS digit-ordered stage ->
// coalesced copy-out. Stability: sub = k*16+wave is monotone in position.
template <bool IS_SRC, int P>
__device__ void run_pass(SortSmem& sm, const float* __restrict__ rawA,
                         const float* __restrict__ rawS,
                         const uint32_t* __restrict__ inBuf,
                         uint32_t* __restrict__ outBuf)
{
    constexpr int DBITS = (P == 0) ? 8 : 7;
    constexpr int ND = 1 << DBITS;
    constexpr int DSH = (P == 0) ? 10 : (P == 1 ? 18 : 25);  // digit shift in staged val
    constexpr bool P0SRC = IS_SRC && (P == 0);

    const int tid = threadIdx.x;
    const int lane = tid & 63;
    const int wave = tid >> 6;
    const uint64_t lane_lt = (1ull << lane) - 1ull;

    // ---- pass start: sbase[0] = exclusive scan of hist; zero hist for reuse ----
    {
        uint32_t h = 0u, incl = 0u;
        if (tid < ND) {
            h = sm.hist[tid];
            sm.hist[tid] = 0u;
            incl = h;
#pragma unroll
            for (int dd = 1; dd < 64; dd <<= 1) {
                uint32_t t = __shfl_up(incl, dd, 64);
                if (lane >= dd) incl += t;
            }
            if (lane == 63) sm.wavesum[tid >> 6] = incl;
        }
        __syncthreads();
        if (tid < ND) {
            uint32_t woff = 0u;
#pragma unroll
            for (int j = 0; j < ND / 64; ++j)
                if (j < (tid >> 6)) woff += sm.wavesum[j];
            sm.sbase[0][tid] = woff + incl - h;
        }
        __syncthreads();
    }

    // returns {value, digit}
    auto loadE = [&](int c, int k) -> uint2 {
        const int pos = c * CHUNK + (k << 10) + (wave << 6) + lane;
        if constexpr (P == 0) {
            float av = rawA[pos];
            uint32_t kk = fkey(av);
            if constexpr (IS_SRC) {
                float sv = rawS[pos];
                uint32_t o = ((kk >> 18) << 18) | (uint32_t)pos;
                if (av < 0.f) o |= 1u << 16;
                if (sv < 0.f) o |= 1u << 17;
                return make_uint2(o, (kk >> 10) & 255u);
            } else {
                return make_uint2(kk, (kk >> 10) & 255u);
            }
        } else {
            uint32_t v = inBuf[pos];
            return make_uint2(v, (v >> DSH) & (ND - 1));
        }
    };

    uint2 e[EPT];
#pragma unroll
    for (int k = 0; k < EPT; ++k) e[k] = loadE(0, k);

    for (int c = 0; c < NCHUNK; ++c) {
        const int par = c & 1;

        // ---- zero own whist rows (wave-private, no hazard) ----
        {
            uint4 z = make_uint4(0u, 0u, 0u, 0u);
#pragma unroll
            for (int k = 0; k < EPT; ++k) {
                uint4* rp = (uint4*)&sm.whist[(k * 16 + wave) * ND];
                if (lane < ND / 8) rp[lane] = z;
            }
        }

        // ---- ballot-rank all 4 elements (independent mask chains -> ILP) ----
        uint32_t rw[EPT];
#pragma unroll
        for (int k = 0; k < EPT; ++k) {
            const uint32_t d = e[k].y;
            uint64_t m = ~0ull;
#pragma unroll
            for (int b = 0; b < DBITS; ++b) {
                uint64_t bal = __ballot((d >> b) & 1u);
                m &= ((d >> b) & 1u) ? bal : ~bal;
            }
            rw[k] = (uint32_t)__popcll(m & lane_lt);
            if (rw[k] == 0u)
                sm.whist[(k * 16 + wave) * ND + d] = (uint16_t)__popcll(m);
        }

        // ---- fused histogram for next pass ----
        if constexpr (P == 0) {
            // next digit = bits 18-24 (mostly mantissa): plain atomics
#pragma unroll
            for (int k = 0; k < EPT; ++k)
                atomicAdd(&sm.hist[(e[k].x >> 18) & 127u], 1u);
        } else if constexpr (P == 1) {
            // next digit = exponent bits 25-31: skewed -> leader-aggregated
#pragma unroll
            for (int k = 0; k < EPT; ++k) {
                const uint32_t nd = (e[k].x >> 25) & 127u;
                uint64_t m = ~0ull;
#pragma unroll
                for (int b = 0; b < 7; ++b) {
                    uint64_t bal = __ballot((nd >> b) & 1u);
                    m &= ((nd >> b) & 1u) ? bal : ~bal;
                }
                if ((m & lane_lt) == 0ull)
                    atomicAdd(&sm.hist[nd], (uint32_t)__popcll(m));
            }
        }
        __syncthreads();  // b1: whist counts complete

        // ---- scan A: per-digit totals + wave-level inclusive scan ----
        uint32_t tot = 0u, incl = 0u;
        if (tid < ND) {
#pragma unroll
            for (int s = 0; s < SUBS; ++s) tot += sm.whist[s * ND + tid];
            incl = tot;
#pragma unroll
            for (int dd = 1; dd < 64; dd <<= 1) {
                uint32_t t = __shfl_up(incl, dd, 64);
                if (lane >= dd) incl += t;
            }
            if (lane == 63) sm.wavesum[tid >> 6] = incl;
        }
        __syncthreads();  // b1.5

        // ---- scan B: local starts -> whist local prefixes; adj & next sbase ----
        if (tid < ND) {
            uint32_t woff = 0u;
#pragma unroll
            for (int j = 0; j < ND / 64; ++j)
                if (j < (tid >> 6)) woff += sm.wavesum[j];
            const uint32_t ls = woff + incl - tot;
            uint32_t run = ls;
#pragma unroll
            for (int s = 0; s < SUBS; ++s) {
                uint32_t t = sm.whist[s * ND + tid];
                sm.whist[s * ND + tid] = (uint16_t)run;
                run += t;
            }
            const uint32_t sb = sm.sbase[par][tid];
            sm.adj[par][tid] = sb - ls;
            sm.sbase[par ^ 1][tid] = sb + (run - ls);
        }
        __syncthreads();  // b2: local offsets ready

        // ---- LDS stage scatter + global prefetch for next chunk ----
#pragma unroll
        for (int k = 0; k < EPT; ++k) {
            const uint32_t s = (uint32_t)sm.whist[(k * 16 + wave) * ND + e[k].y]
                               + rw[k];
            sm.stage[s] = e[k].x;
            if constexpr (P0SRC) sm.dstg[s] = (uint8_t)e[k].y;
        }
        uint2 n[EPT];
#pragma unroll
        for (int k = 0; k < EPT; ++k) n[k] = make_uint2(0u, 0u);
        if (c + 1 < NCHUNK) {
#pragma unroll
            for (int k = 0; k < EPT; ++k) n[k] = loadE(c + 1, k);
        }
        __syncthreads();  // b3: stage complete

        // ---- coalesced copy-out: slot i -> adj[d] + i ----
#pragma unroll
        for (int h = 0; h < EPT; ++h) {
            const int slot = tid + (h << 10);
            const uint32_t u = sm.stage[slot];
            uint32_t d;
            if constexpr (P0SRC) d = sm.dstg[slot];
            else                 d = (u >> DSH) & (ND - 1);
            const uint32_t go = sm.adj[par][d] + (uint32_t)slot;
            uint32_t ov = u;
            if constexpr (IS_SRC && P == 2) ov = u & 0x3FFFFu;  // idx+signs only
            outBuf[go] = ov;
        }
#pragma unroll
        for (int k = 0; k < EPT; ++k) e[k] = n[k];
    }
    __syncthreads();  // seal pass: writes drained before next pass reads
}

__device__ __forceinline__ float detail_one(float c, float s) {
    const float f = (c < 0.f) ? ((s < 0.f) ? -1.f : COS_04PI)
                              : ((s < 0.f) ? -COS_04PI : 1.f);
    return (0.4f * fabsf(c) + 0.6f * fabsf(s)) * f;
}

} // namespace

__global__ __launch_bounds__(ST, 8)
void sort_kernel(const float* __restrict__ ca, const float* __restrict__ sa,
                 uint32_t* srcA, uint32_t* srcB,
                 uint32_t* tgtA, uint32_t* tgtB, uint32_t* tgtF)
{
    __shared__ SortSmem sm;
    const int row = blockIdx.x >> 1;
    if (threadIdx.x < 256) sm.hist[threadIdx.x] = 0u;
    __syncthreads();

    if ((blockIdx.x & 1) == 0) {
        const float* cRow = ca + (size_t)row * ROW_N;
        const float* sRow = sa + (size_t)row * ROW_N;
        uint32_t* A = srcA + (size_t)row * ROW_N;
        uint32_t* B = srcB + (size_t)row * ROW_N;
        prepass_hist(sm, cRow);
        run_pass<true, 0>(sm, cRow, sRow, nullptr, A);
        run_pass<true, 1>(sm, nullptr, nullptr, A, B);
        run_pass<true, 2>(sm, nullptr, nullptr, B, A);  // final: back into A (srcF)
    } else {
        const float* sRow = sa + (size_t)row * ROW_N;
        uint32_t* A = tgtA + (size_t)row * ROW_N;
        uint32_t* B = tgtB + (size_t)row * ROW_N;
        uint32_t* F = tgtF + (size_t)row * ROW_N;
        prepass_hist(sm, sRow);
        run_pass<false, 0>(sm, sRow, nullptr, nullptr, A);
        run_pass<false, 1>(sm, nullptr, nullptr, A, B);
        run_pass<false, 2>(sm, nullptr, nullptr, B, F);
    }
}

// out0[row, idx] = t_sorted[row, k] * cos(0.8*ph(c) + 0.2*ph(s))
// srcF flat u32 [ROWS][ROW_N]: idx16 | cneg<<16 | sneg<<17 (rank order).
// tgtF flat u32 [ROWS][ROW_N]: exact |style| float bits, sorted.
__global__ __launch_bounds__(256)
void approx_finalize(const uint32_t* __restrict__ srcF,
                     const uint32_t* __restrict__ tgtF,
                     float* __restrict__ out0)
{
    const size_t kk = (size_t)blockIdx.x * blockDim.x + threadIdx.x;
    const uint32_t v = srcF[kk];
    const size_t j = ((kk >> 16) << 16) | (v & 0xFFFFu);
    const float t = __uint_as_float(tgtF[kk]);
    const uint32_t cneg = (v >> 16) & 1u;
    const uint32_t sneg = (v >> 17) & 1u;
    const float f = cneg ? (sneg ? -1.f : -COS_02PI)
                         : (sneg ? COS_02PI : 1.f);
    out0[j] = t * f;
}

__global__ __launch_bounds__(256)
void details_kernel(const float4* __restrict__ ch, const float4* __restrict__ sh,
                    const float4* __restrict__ cv, const float4* __restrict__ sv,
                    const float4* __restrict__ cd, const float4* __restrict__ sd,
                    float4* __restrict__ oh, float4* __restrict__ ov,
                    float4* __restrict__ od)
{
    const size_t i = (size_t)blockIdx.x * blockDim.x + threadIdx.x;
    float4 a, b, r;
    a = ch[i]; b = sh[i];
    r.x = detail_one(a.x, b.x); r.y = detail_one(a.y, b.y);
    r.z = detail_one(a.z, b.z); r.w = detail_one(a.w, b.w);
    oh[i] = r;
    a = cv[i]; b = sv[i];
    r.x = detail_one(a.x, b.x); r.y = detail_one(a.y, b.y);
    r.z = detail_one(a.z, b.z); r.w = detail_one(a.w, b.w);
    ov[i] = r;
    a = cd[i]; b = sd[i];
    r.x = detail_one(a.x, b.x); r.y = detail_one(a.y, b.y);
    r.z = detail_one(a.z, b.z); r.w = detail_one(a.w, b.w);
    od[i] = r;
}

extern "C" void kernel_launch(void* const* d_in, const int* in_sizes, int n_in,
                              void* d_out, int out_size, void* d_ws, size_t ws_size,
                              hipStream_t stream)
{
    (void)in_sizes; (void)n_in; (void)out_size; (void)ws_size;
    const float* ca = (const float*)d_in[0];
    const float* ch = (const float*)d_in[1];
    const float* cv = (const float*)d_in[2];
    const float* cd = (const float*)d_in[3];
    const float* sa = (const float*)d_in[4];
    const float* sh = (const float*)d_in[5];
    const float* sv = (const float*)d_in[6];
    const float* sd = (const float*)d_in[7];

    float* out = (float*)d_out;
    float* out_a = out;
    float* out_h = out + NTOT;
    float* out_v = out + 2 * NTOT;
    float* out_d = out + 3 * NTOT;

    // Buffers (all u32; ws >= 134 MB, proven by prior rounds):
    //  src: P0 raw -> srcA (ws[0,67MB)); P1 srcA -> srcB (ws[67,134MB));
    //       P2 srcB -> srcA (= srcF, flat idx+signs in rank order).
    //  tgt: P0 -> out_d slice; P1 -> out_h slice; P2 -> out_v (tgtF, sorted keys).
    //  finalize reads srcF (ws) + tgtF (out_v) BEFORE details overwrites h/v/d.
    uint32_t* srcA = (uint32_t*)d_ws;
    uint32_t* srcB = (uint32_t*)((char*)d_ws + NTOT * 4);
    uint32_t* tgtA = (uint32_t*)out_d;
    uint32_t* tgtB = (uint32_t*)out_h;
    uint32_t* tgtF = (uint32_t*)out_v;

    sort_kernel<<<2 * ROWS, ST, 0, stream>>>(ca, sa, srcA, srcB, tgtA, tgtB, tgtF);

    approx_finalize<<<(int)(NTOT / 256), 256, 0, stream>>>(
        (const uint32_t*)srcA, (const uint32_t*)tgtF, out_a);

    details_kernel<<<(int)(NTOT / 4 / 256), 256, 0, stream>>>(
        (const float4*)ch, (const float4*)sh,
        (const float4*)cv, (const float4*)sv,
        (const float4*)cd, (const float4*)sd,
        (float4*)out_h, (float4*)out_v, (float4*)out_d);
}